// Round 1
// baseline (254.863 us; speedup 1.0000x reference)
//
#include <hip/hip_runtime.h>
#include <stdint.h>

// Problem constants (fixed by setup_inputs): B=4, N=32768, K=16, nqueries=2048, stride=16.
#define NPTS  32768
#define NQ    2048
#define KNN   16
#define NB    4
#define TS    2048            // LDS tile size in points (24 KB)
#define WAVES_PER_BLOCK 4

// Wave-distributed exact top-16 KNN.
// One wave per query. Lanes 0..15 hold the current sorted top-16 (ascending by
// (dist, idx)). Lane 15's element is the exact threshold tau. Candidates are
// gated against tau (exact, so ~140 accepts/query total) and inserted serially
// via ballot/ffs + shfl_up shift.
__global__ __launch_bounds__(256) void knn_kernel(const float* __restrict__ xyz,
                                                  float* __restrict__ out_idx,
                                                  float* __restrict__ out_pts)
{
    __shared__ float lds[TS * 3];

    const int tid  = threadIdx.x;
    const int lane = tid & 63;
    const int wv   = tid >> 6;
    const int g    = blockIdx.x * WAVES_PER_BLOCK + wv;  // global query id, [0, NB*NQ)
    const int b    = g >> 11;                            // g / NQ
    const int q    = g & (NQ - 1);
    const size_t base = (size_t)b * NPTS * 3;

    // Query point (stride-16 subsample)
    const int qp = q << 4;
    const float qx = xyz[base + 3 * qp + 0];
    const float qy = xyz[base + 3 * qp + 1];
    const float qz = xyz[base + 3 * qp + 2];

    if (lane == 0) {
        out_pts[3 * g + 0] = qx;
        out_pts[3 * g + 1] = qy;
        out_pts[3 * g + 2] = qz;
    }

    // Distributed list element (valid in lanes 0..15), initialized empty.
    float ld = __builtin_inff();
    int   li = 0x7fffffff;
    float tau_d = __builtin_inff();
    int   tau_i = 0x7fffffff;

    for (int tile = 0; tile < NPTS; tile += TS) {
        __syncthreads();  // previous tile fully consumed
        // Stage TS points (TS*3 floats = 1536 float4) cooperatively.
        const float4* src = (const float4*)(xyz + base + (size_t)tile * 3);
        float4* dst = (float4*)lds;
        #pragma unroll
        for (int t = 0; t < (TS * 3 / 4) / 256; ++t)
            dst[tid + t * 256] = src[tid + t * 256];
        __syncthreads();

        for (int i = lane; i < TS; i += 64) {
            const float x = lds[3 * i + 0];
            const float y = lds[3 * i + 1];
            const float z = lds[3 * i + 2];
            // Match numpy exactly: ((dx*dx + dy*dy) + dz*dz), no FMA contraction.
            const float dx = __fadd_rn(x, -qx);
            const float dy = __fadd_rn(y, -qy);
            const float dz = __fadd_rn(z, -qz);
            const float d  = __fadd_rn(__fadd_rn(__fmul_rn(dx, dx), __fmul_rn(dy, dy)),
                                       __fmul_rn(dz, dz));
            const int p = tile + i;

            const bool accept = (d < tau_d) || (d == tau_d && p < tau_i);
            unsigned long long am = __ballot(accept);
            if (am) {
                do {
                    const int srcl = __ffsll(am) - 1;
                    am &= am - 1;
                    const float wd = __shfl(d, srcl);
                    const int   wi = __shfl(p, srcl);
                    // position = #elements strictly less than (wd, wi)
                    const bool less = (ld < wd) || (ld == wd && li < wi);
                    const unsigned long long lm = __ballot(less);
                    const int pos = __popcll(lm & 0xffffull);
                    const float pld = __shfl_up(ld, 1);
                    const int   pli = __shfl_up(li, 1);
                    if (lane < KNN) {
                        if (lane == pos)      { ld = wd;  li = wi;  }
                        else if (lane > pos)  { ld = pld; li = pli; }
                        // pos == 16 -> candidate worse than all 16 -> no-op
                    }
                } while (am);
                tau_d = __shfl(ld, 15);
                tau_i = __shfl(li, 15);
            }
        }
    }

    // Lanes 0..15 hold ranks 0..15 sorted ascending -> coalesced store.
    if (lane < KNN) {
        out_idx[(size_t)g * KNN + lane] = (float)li;
    }
}

extern "C" void kernel_launch(void* const* d_in, const int* in_sizes, int n_in,
                              void* d_out, int out_size, void* d_ws, size_t ws_size,
                              hipStream_t stream) {
    const float* xyz = (const float*)d_in[0];
    float* out = (float*)d_out;
    float* out_idx = out;                                 // NB*NQ*KNN floats
    float* out_pts = out + (size_t)NB * NQ * KNN;         // NB*NQ*3 floats

    const int nqueries_total = NB * NQ;                   // 8192
    const int blocks = nqueries_total / WAVES_PER_BLOCK;  // 2048
    knn_kernel<<<blocks, 256, 0, stream>>>(xyz, out_idx, out_pts);
}